// Round 1
// baseline (254.930 us; speedup 1.0000x reference)
//
#include <hip/hip_runtime.h>

__device__ __forceinline__ float smooth_l1(float a, float b) {
    float d = a - b;
    float ad = fabsf(d);
    return (ad < 1.0f) ? 0.5f * d * d : ad - 0.5f;
}

__global__ __launch_bounds__(256) void mask_criterion_kernel(
    const float* __restrict__ inputs,
    const float* __restrict__ targets,
    const int* __restrict__ mask,
    float* __restrict__ out,
    int D)
{
    const int row = blockIdx.x;
    const int m = mask[row];
    if (m == 0) return;  // block-uniform early exit: skip the whole row's traffic

    const float4* __restrict__ a = (const float4*)(inputs + (size_t)row * D);
    const float4* __restrict__ b = (const float4*)(targets + (size_t)row * D);
    const int nvec = D >> 2;  // 2048 float4 per row

    float sum = 0.0f;
    // coalesced: consecutive lanes hit consecutive float4s each iteration
    for (int i = threadIdx.x; i < nvec; i += 256) {
        float4 x = a[i];
        float4 y = b[i];
        sum += smooth_l1(x.x, y.x);
        sum += smooth_l1(x.y, y.y);
        sum += smooth_l1(x.z, y.z);
        sum += smooth_l1(x.w, y.w);
    }

    // 64-lane wave reduction
    #pragma unroll
    for (int off = 32; off > 0; off >>= 1)
        sum += __shfl_down(sum, off, 64);

    __shared__ float wsum[4];
    const int lane = threadIdx.x & 63;
    const int wid  = threadIdx.x >> 6;
    if (lane == 0) wsum[wid] = sum;
    __syncthreads();

    if (threadIdx.x == 0) {
        float s = wsum[0] + wsum[1] + wsum[2] + wsum[3];
        // per-sample mean, scaled by mask value, summed over rows
        atomicAdd(out, s * (float)m / (float)D);
    }
}

extern "C" void kernel_launch(void* const* d_in, const int* in_sizes, int n_in,
                              void* d_out, int out_size, void* d_ws, size_t ws_size,
                              hipStream_t stream) {
    const float* inputs  = (const float*)d_in[0];
    const float* targets = (const float*)d_in[1];
    const int*   mask    = (const int*)d_in[2];
    float* out = (float*)d_out;

    const int B = in_sizes[2];          // mask has B elements
    const int D = in_sizes[0] / B;      // 8192

    // d_out is poisoned with 0xAA before every timed launch — zero it first.
    hipMemsetAsync(d_out, 0, (size_t)out_size * sizeof(float), stream);

    mask_criterion_kernel<<<dim3(B), dim3(256), 0, stream>>>(inputs, targets, mask, out, D);
}

// Round 2
// 248.991 us; speedup vs baseline: 1.0238x; 1.0238x over previous
//
#include <hip/hip_runtime.h>

__device__ __forceinline__ float smooth_l1(float a, float b) {
    float d = a - b;
    float ad = fabsf(d);
    return (ad < 1.0f) ? 0.5f * d * d : ad - 0.5f;
}

// Stage A: one block per row. Writes per-row contribution (mean * mask) to ws[row].
// Masked rows write 0.0 (ws is poisoned with 0xAA, so every slot must be written).
__global__ __launch_bounds__(256) void row_loss_kernel(
    const float* __restrict__ inputs,
    const float* __restrict__ targets,
    const int* __restrict__ mask,
    float* __restrict__ ws,
    int D)
{
    const int row = blockIdx.x;
    const int m = mask[row];
    if (m == 0) {
        // block-uniform early exit: skip all HBM traffic for this row
        if (threadIdx.x == 0) ws[row] = 0.0f;
        return;
    }

    const float4* __restrict__ a = (const float4*)(inputs + (size_t)row * D);
    const float4* __restrict__ b = (const float4*)(targets + (size_t)row * D);
    const int nvec = D >> 2;  // 2048 float4 per row

    float sum = 0.0f;
    for (int i = threadIdx.x; i < nvec; i += 256) {
        float4 x = a[i];
        float4 y = b[i];
        sum += smooth_l1(x.x, y.x);
        sum += smooth_l1(x.y, y.y);
        sum += smooth_l1(x.z, y.z);
        sum += smooth_l1(x.w, y.w);
    }

    // 64-lane wave reduction
    #pragma unroll
    for (int off = 32; off > 0; off >>= 1)
        sum += __shfl_down(sum, off, 64);

    __shared__ float wsum[4];
    const int lane = threadIdx.x & 63;
    const int wid  = threadIdx.x >> 6;
    if (lane == 0) wsum[wid] = sum;
    __syncthreads();

    if (threadIdx.x == 0) {
        float s = wsum[0] + wsum[1] + wsum[2] + wsum[3];
        ws[row] = s * (float)m / (float)D;
    }
}

// Stage B: single block reduces B per-row values; sole writer of out[0]
// (no memset of d_out needed despite 0xAA poison).
__global__ __launch_bounds__(256) void final_reduce_kernel(
    const float* __restrict__ ws,
    float* __restrict__ out,
    int B)
{
    float sum = 0.0f;
    const float4* __restrict__ w4 = (const float4*)ws;
    const int nvec = B >> 2;  // 1024 float4
    for (int i = threadIdx.x; i < nvec; i += 256) {
        float4 v = w4[i];
        sum += v.x + v.y + v.z + v.w;
    }

    #pragma unroll
    for (int off = 32; off > 0; off >>= 1)
        sum += __shfl_down(sum, off, 64);

    __shared__ float wsum[4];
    const int lane = threadIdx.x & 63;
    const int wid  = threadIdx.x >> 6;
    if (lane == 0) wsum[wid] = sum;
    __syncthreads();

    if (threadIdx.x == 0)
        out[0] = wsum[0] + wsum[1] + wsum[2] + wsum[3];
}

extern "C" void kernel_launch(void* const* d_in, const int* in_sizes, int n_in,
                              void* d_out, int out_size, void* d_ws, size_t ws_size,
                              hipStream_t stream) {
    const float* inputs  = (const float*)d_in[0];
    const float* targets = (const float*)d_in[1];
    const int*   mask    = (const int*)d_in[2];
    float* out = (float*)d_out;
    float* ws  = (float*)d_ws;

    const int B = in_sizes[2];          // mask has B elements
    const int D = in_sizes[0] / B;      // 8192

    row_loss_kernel<<<dim3(B), dim3(256), 0, stream>>>(inputs, targets, mask, ws, D);
    final_reduce_kernel<<<dim3(1), dim3(256), 0, stream>>>(ws, out, B);
}